// Round 9
// baseline (381.354 us; speedup 1.0000x reference)
//
#include <hip/hip_runtime.h>
#include <math.h>

#define B_  4
#define L_  2048
#define H_  1024
#define NH_ 16
#define DK_ 64

// 0.125 * log2(e): folded into q so attn scores are already in log2 units
#define QSC 0.18033688011112043f

typedef unsigned short ushort_t;
typedef __attribute__((ext_vector_type(8))) short short8;
typedef __attribute__((ext_vector_type(4))) float f32x4;

__device__ __forceinline__ ushort_t f2b(float f) {   // RNE fp32->bf16
    unsigned int u = __float_as_uint(f);
    return (ushort_t)((u + 0x7FFFu + ((u >> 16) & 1u)) >> 16);
}
__device__ __forceinline__ float b2f(ushort_t h) {
    return __uint_as_float(((unsigned int)h) << 16);
}
__device__ __forceinline__ float fexp2(float x) {
    return __builtin_amdgcn_exp2f(x);
}

__device__ __forceinline__ void gload_lds16(const void* g, void* l) {
    __builtin_amdgcn_global_load_lds((const __attribute__((address_space(1))) void*)g,
                                     (__attribute__((address_space(3))) void*)l, 16, 0, 0);
}

// ---------------------------------------------------------------------------
// RNE split cast for x, Wq, Wk in ONE launch (block ranges select the input)
// ---------------------------------------------------------------------------
__global__ __launch_bounds__(256) void fsplit3_kernel(
    const float* __restrict__ x, const float* __restrict__ Wq, const float* __restrict__ Wk,
    ushort_t* __restrict__ xh, ushort_t* __restrict__ xl,
    ushort_t* __restrict__ wqh, ushort_t* __restrict__ wql,
    ushort_t* __restrict__ wkh, ushort_t* __restrict__ wkl)
{
    int bid = blockIdx.x;
    const float* src; ushort_t *ph, *pl; int i;
    if (bid < 8192)      { src = x;  ph = xh;  pl = xl;  i = bid * 256 + threadIdx.x; }
    else if (bid < 9216) { src = Wq; ph = wqh; pl = wql; i = (bid - 8192) * 256 + threadIdx.x; }
    else                 { src = Wk; ph = wkh; pl = wkl; i = (bid - 9216) * 256 + threadIdx.x; }
    float4 v = ((const float4*)src)[i];
    float f[4] = {v.x, v.y, v.z, v.w};
    ushort4 h, l;
    ushort_t hh[4], ll[4];
    #pragma unroll
    for (int e = 0; e < 4; ++e) {
        hh[e] = f2b(f[e]);
        ll[e] = f2b(f[e] - b2f(hh[e]));
    }
    h.x = hh[0]; h.y = hh[1]; h.z = hh[2]; h.w = hh[3];
    l.x = ll[0]; l.y = ll[1]; l.z = ll[2]; l.w = ll[3];
    ((ushort4*)ph)[i] = h;
    ((ushort4*)pl)[i] = l;
}

// ---------------------------------------------------------------------------
// Q/K projection from pre-split x planes. 128x128 tile, BK=32, 256 threads.
// z=0 (q): 2 MFMAs (ah+al)*Wh, output hi only, prescaled by QSC.
// z=1 (k): 3 MFMAs (al*Wh + ah*Wl + ah*Wh), output split (hi,lo).
// ---------------------------------------------------------------------------
__global__ __launch_bounds__(256) void proj_split(
    const ushort_t* __restrict__ xh, const ushort_t* __restrict__ xl,
    const ushort_t* __restrict__ Wqh,
    const ushort_t* __restrict__ Wkh, const ushort_t* __restrict__ Wkl,
    const float* __restrict__ bq, const float* __restrict__ bk,
    ushort_t* __restrict__ qho,
    ushort_t* __restrict__ kho, ushort_t* __restrict__ klo)
{
    const int z = blockIdx.z;
    const ushort_t* Wh = z ? Wkh : Wqh;
    const ushort_t* Wl = Wkl;
    const float* bias  = z ? bk  : bq;

    const int n0 = blockIdx.y * 128;
    const int o0 = blockIdx.x * 128;

    __shared__ ushort_t Ash[128 * 32];
    __shared__ ushort_t Asl[128 * 32];
    __shared__ ushort_t Bsh[128 * 32];
    __shared__ ushort_t Bsl[128 * 32];

    const int t = threadIdx.x;
    const int lane = t & 63, w = t >> 6;
    const int ln = lane & 15, qd = lane >> 4;
    const int wy = w >> 1, wx = w & 1;
    const int ldsbase = (t & ~63) * 8;

    int rowS[2], cS[2];
    #pragma unroll
    for (int i = 0; i < 2; ++i) {
        int slot = i * 256 + t;
        rowS[i] = slot >> 2;
        cS[i] = (slot & 3) ^ ((rowS[i] >> 1) & 3);
    }

    f32x4 acc[4][4];
    #pragma unroll
    for (int i = 0; i < 4; ++i)
        #pragma unroll
        for (int j = 0; j < 4; ++j) acc[i][j] = (f32x4){0.f, 0.f, 0.f, 0.f};

    for (int k0 = 0; k0 < H_; k0 += 32) {
        __syncthreads();
        #pragma unroll
        for (int i = 0; i < 2; ++i) {
            gload_lds16(xh + (size_t)(n0 + rowS[i]) * H_ + k0 + cS[i] * 8,
                        &Ash[i * 2048 + ldsbase]);
            gload_lds16(xl + (size_t)(n0 + rowS[i]) * H_ + k0 + cS[i] * 8,
                        &Asl[i * 2048 + ldsbase]);
            gload_lds16(Wh + (size_t)(o0 + rowS[i]) * H_ + k0 + cS[i] * 8,
                        &Bsh[i * 2048 + ldsbase]);
        }
        if (z) {
            #pragma unroll
            for (int i = 0; i < 2; ++i)
                gload_lds16(Wl + (size_t)(o0 + rowS[i]) * H_ + k0 + cS[i] * 8,
                            &Bsl[i * 2048 + ldsbase]);
        }
        __syncthreads();

        short8 bh4[4], bl4[4];
        #pragma unroll
        for (int nt = 0; nt < 4; ++nt) {
            int row = wx * 64 + nt * 16 + ln;
            int sz = (qd ^ ((row >> 1) & 3)) << 3;
            bh4[nt] = *(const short8*)&Bsh[row * 32 + sz];
            if (z) bl4[nt] = *(const short8*)&Bsl[row * 32 + sz];
        }
        #pragma unroll
        for (int mt = 0; mt < 4; ++mt) {
            int row = wy * 64 + mt * 16 + ln;
            int sz = (qd ^ ((row >> 1) & 3)) << 3;
            short8 ah = *(const short8*)&Ash[row * 32 + sz];
            short8 al = *(const short8*)&Asl[row * 32 + sz];
            if (z) {
                #pragma unroll
                for (int nt = 0; nt < 4; ++nt) {
                    acc[mt][nt] = __builtin_amdgcn_mfma_f32_16x16x32_bf16(al, bh4[nt], acc[mt][nt], 0, 0, 0);
                    acc[mt][nt] = __builtin_amdgcn_mfma_f32_16x16x32_bf16(ah, bl4[nt], acc[mt][nt], 0, 0, 0);
                    acc[mt][nt] = __builtin_amdgcn_mfma_f32_16x16x32_bf16(ah, bh4[nt], acc[mt][nt], 0, 0, 0);
                }
            } else {
                #pragma unroll
                for (int nt = 0; nt < 4; ++nt) {
                    acc[mt][nt] = __builtin_amdgcn_mfma_f32_16x16x32_bf16(al, bh4[nt], acc[mt][nt], 0, 0, 0);
                    acc[mt][nt] = __builtin_amdgcn_mfma_f32_16x16x32_bf16(ah, bh4[nt], acc[mt][nt], 0, 0, 0);
                }
            }
        }
    }

    #pragma unroll
    for (int nt = 0; nt < 4; ++nt) {
        int o = o0 + wx * 64 + nt * 16 + ln;
        float bvv = bias[o];
        int hh = o >> 6, d = o & 63;
        #pragma unroll
        for (int mt = 0; mt < 4; ++mt) {
            #pragma unroll
            for (int r = 0; r < 4; ++r) {
                int n = n0 + wy * 64 + mt * 16 + qd * 4 + r;
                int bb = n >> 11, l = n & (L_ - 1);
                size_t idx = (((size_t)(bb * NH_ + hh) * L_ + l) << 6) + d;
                float val = acc[mt][nt][r] + bvv;
                if (z) {
                    ushort_t vh = f2b(val);
                    kho[idx] = vh;
                    klo[idx] = f2b(val - b2f(vh));
                } else {
                    qho[idx] = f2b(val * QSC);
                }
            }
        }
    }
}

// ---------------------------------------------------------------------------
// Attention column sums cs[b,h,k] = sum_q P[q,k]. q-tile 128/block, 2 A-sets
// per wave. Double-buffered K staging: ONE barrier per kt; prefetch kt+1
// issued right after the barrier so it flies during compute. Column sums go
// straight to global atomics per wave (no LDS reduction barrier).
// ---------------------------------------------------------------------------
__global__ __launch_bounds__(256) void attn_split(
    const ushort_t* __restrict__ qh,
    const ushort_t* __restrict__ kh, const ushort_t* __restrict__ kl,
    float* __restrict__ cs)
{
    const int qt = blockIdx.x & 15;        // 16 q-tiles of 128 rows
    const int bh = blockIdx.x >> 4;

    const int t = threadIdx.x;
    const int lane = t & 63, w = t >> 6;
    const int ln = lane & 15, qd = lane >> 4;

    __shared__ ushort_t Ksh[2][64 * 64];
    __shared__ ushort_t Ksl[2][64 * 64];

    const size_t headoff = (size_t)bh * L_ * DK_;
    const size_t qoff0 = headoff + ((size_t)(qt * 128 + w * 32 + ln)) * DK_;
    const size_t qoff1 = qoff0 + 16 * DK_;
    short8 aqh[2][2];
    aqh[0][0] = *(const short8*)(qh + qoff0 + qd * 8);
    aqh[0][1] = *(const short8*)(qh + qoff0 + 32 + qd * 8);
    aqh[1][0] = *(const short8*)(qh + qoff1 + qd * 8);
    aqh[1][1] = *(const short8*)(qh + qoff1 + 32 + qd * 8);

    int rowS[2], cS[2];
    #pragma unroll
    for (int i = 0; i < 2; ++i) {
        int slot = i * 256 + t;
        rowS[i] = slot >> 3;
        cS[i] = (slot & 7) ^ (rowS[i] & 7);
    }
    const int ldsb = (t & ~63) * 8;
    // running global pointers for this thread's staging slots (advance 4096/kt)
    const ushort_t* pkh[2];
    const ushort_t* pkl[2];
    #pragma unroll
    for (int i = 0; i < 2; ++i) {
        pkh[i] = kh + headoff + ((size_t)rowS[i] << 6) + cS[i] * 8;
        pkl[i] = kl + headoff + ((size_t)rowS[i] << 6) + cS[i] * 8;
    }

    float l_run[2][4] = {};

    // ---------------- pass 1: l = sum_k exp2(s_hi), dbuf, 1 barrier/kt ----
    {
        const ushort_t* ph[2] = {pkh[0], pkh[1]};
        // stage kt=0 into buf 0
        #pragma unroll
        for (int i = 0; i < 2; ++i)
            gload_lds16(ph[i], &Ksh[0][i * 2048 + ldsb]);

        for (int kt = 0; kt < 32; ++kt) {
            const int cb = kt & 1;
            __syncthreads();                       // drains prefetch for cb
            if (kt + 1 < 32) {
                #pragma unroll
                for (int i = 0; i < 2; ++i)
                    gload_lds16(ph[i] + (size_t)(kt + 1) * 4096,
                                &Ksh[cb ^ 1][i * 2048 + ldsb]);
            }
            #pragma unroll
            for (int nt = 0; nt < 4; ++nt) {
                int kr = nt * 16 + ln;
                int sz0 = ((qd     ^ (kr & 7)) << 3);
                int sz1 = (((qd + 4) ^ (kr & 7)) << 3);
                short8 b0h = *(const short8*)&Ksh[cb][kr * 64 + sz0];
                short8 b1h = *(const short8*)&Ksh[cb][kr * 64 + sz1];
                #pragma unroll
                for (int s = 0; s < 2; ++s) {
                    f32x4 zz = (f32x4){0.f, 0.f, 0.f, 0.f};
                    zz = __builtin_amdgcn_mfma_f32_16x16x32_bf16(aqh[s][0], b0h, zz, 0, 0, 0);
                    zz = __builtin_amdgcn_mfma_f32_16x16x32_bf16(aqh[s][1], b1h, zz, 0, 0, 0);
                    #pragma unroll
                    for (int r = 0; r < 4; ++r)
                        l_run[s][r] += fexp2(zz[r]);
                }
            }
        }
    }

    // stage pass-2 kt=0 (both planes) so it flies during the reduction
    #pragma unroll
    for (int i = 0; i < 2; ++i) {
        gload_lds16(pkh[i], &Ksh[0][i * 2048 + ldsb]);
        gload_lds16(pkl[i], &Ksl[0][i * 2048 + ldsb]);
    }

    #pragma unroll
    for (int off = 1; off < 16; off <<= 1)
        #pragma unroll
        for (int s = 0; s < 2; ++s)
            #pragma unroll
            for (int r = 0; r < 4; ++r)
                l_run[s][r] += __shfl_xor(l_run[s][r], off);
    float inv_l[2][4];
    #pragma unroll
    for (int s = 0; s < 2; ++s)
        #pragma unroll
        for (int r = 0; r < 4; ++r) inv_l[s][r] = 1.0f / l_run[s][r];

    // ---------------- pass 2: column sums, dbuf, 1 barrier/kt -------------
    for (int kt = 0; kt < 32; ++kt) {
        const int cb = kt & 1;
        __syncthreads();
        if (kt + 1 < 32) {
            #pragma unroll
            for (int i = 0; i < 2; ++i) {
                gload_lds16(pkh[i] + (size_t)(kt + 1) * 4096,
                            &Ksh[cb ^ 1][i * 2048 + ldsb]);
                gload_lds16(pkl[i] + (size_t)(kt + 1) * 4096,
                            &Ksl[cb ^ 1][i * 2048 + ldsb]);
            }
        }

        float colp[4];
        #pragma unroll
        for (int nt = 0; nt < 4; ++nt) {
            int kr = nt * 16 + ln;
            int sz0 = ((qd     ^ (kr & 7)) << 3);
            int sz1 = (((qd + 4) ^ (kr & 7)) << 3);
            short8 b0h = *(const short8*)&Ksh[cb][kr * 64 + sz0];
            short8 b1h = *(const short8*)&Ksh[cb][kr * 64 + sz1];
            short8 b0l = *(const short8*)&Ksl[cb][kr * 64 + sz0];
            short8 b1l = *(const short8*)&Ksl[cb][kr * 64 + sz1];
            float cp = 0.f;
            #pragma unroll
            for (int s = 0; s < 2; ++s) {
                f32x4 zz = (f32x4){0.f, 0.f, 0.f, 0.f};
                zz = __builtin_amdgcn_mfma_f32_16x16x32_bf16(aqh[s][0], b0l, zz, 0, 0, 0);
                zz = __builtin_amdgcn_mfma_f32_16x16x32_bf16(aqh[s][1], b1l, zz, 0, 0, 0);
                zz = __builtin_amdgcn_mfma_f32_16x16x32_bf16(aqh[s][0], b0h, zz, 0, 0, 0);
                zz = __builtin_amdgcn_mfma_f32_16x16x32_bf16(aqh[s][1], b1h, zz, 0, 0, 0);
                cp += fexp2(zz[0]) * inv_l[s][0] + fexp2(zz[1]) * inv_l[s][1]
                    + fexp2(zz[2]) * inv_l[s][2] + fexp2(zz[3]) * inv_l[s][3];
            }
            colp[nt] = cp;
        }
        #pragma unroll
        for (int nt = 0; nt < 4; ++nt) {
            colp[nt] += __shfl_xor(colp[nt], 16);
            colp[nt] += __shfl_xor(colp[nt], 32);
        }
        // lane owns col nt==qd: nt*16+ln == lane; wave-level partial -> atomic
        float mine = (qd == 0) ? colp[0] : (qd == 1) ? colp[1] : (qd == 2) ? colp[2] : colp[3];
        atomicAdd(&cs[(size_t)bh * L_ + kt * 64 + lane], mine);
    }
}

// ---------------------------------------------------------------------------
// T[b,h,h'] = sum_l cs[b,h,l] * x[b,l,h']   (fp32, atomic over 8 l-splits)
// ---------------------------------------------------------------------------
__global__ __launch_bounds__(256) void ctx1_kernel(
    const float* __restrict__ cs, const float* __restrict__ x, float* __restrict__ T)
{
    const int o0 = blockIdx.x * 64, b = blockIdx.y, l0 = blockIdx.z * 256;
    const int t = threadIdx.x, o = t & 63, hg = t >> 6;
    __shared__ float cs_s[16][128];
    float acc[4] = {};

    for (int ch = 0; ch < 2; ++ch) {
        int lbase = l0 + ch * 128;
        __syncthreads();
        for (int i = t; i < 2048; i += 256) {
            int h = i >> 7, lc = i & 127;
            cs_s[h][lc] = cs[((size_t)(b * NH_ + h) << 11) + lbase + lc];
        }
        __syncthreads();
        for (int lc = 0; lc < 128; ++lc) {
            float xv = x[((size_t)(b * L_ + lbase + lc) << 10) + o0 + o];
            #pragma unroll
            for (int j = 0; j < 4; ++j) acc[j] += cs_s[hg * 4 + j][lc] * xv;
        }
    }
    #pragma unroll
    for (int j = 0; j < 4; ++j)
        atomicAdd(&T[((size_t)(b * NH_ + hg * 4 + j) << 10) + o0 + o], acc[j]);
}

// ---------------------------------------------------------------------------
// ctx[b,o] = sum_h' T[b, o>>6, h'] * Wv[o,h'] + L*bv[o]; wave per row
// ---------------------------------------------------------------------------
__global__ __launch_bounds__(256) void ctx2_kernel(
    const float* __restrict__ T, const float* __restrict__ Wv,
    const float* __restrict__ bv, float* __restrict__ ctx)
{
    const int gid  = blockIdx.x * 4 + (threadIdx.x >> 6);
    const int lane = threadIdx.x & 63;
    const int b = gid >> 10, o = gid & (H_ - 1);
    const float4* wr = (const float4*)(Wv + (size_t)o * H_);
    const float4* tr = (const float4*)(T + ((size_t)(b * NH_ + (o >> 6)) << 10));
    float acc = 0.f;
    #pragma unroll
    for (int i = 0; i < 4; ++i) {
        float4 wv = wr[lane + i * 64];
        float4 tv = tr[lane + i * 64];
        acc += wv.x * tv.x + wv.y * tv.y + wv.z * tv.z + wv.w * tv.w;
    }
    #pragma unroll
    for (int off = 32; off; off >>= 1) acc += __shfl_xor(acc, off);
    if (lane == 0) ctx[(b << 10) + o] = acc + (float)L_ * bv[o];
}

// ---------------------------------------------------------------------------
// pooled[b,o] = bo[o] + (1/L) * sum_h ctx[b,h] * Wo[o,h]; wave per row
// ---------------------------------------------------------------------------
__global__ __launch_bounds__(256) void pooled_kernel(
    const float* __restrict__ ctx, const float* __restrict__ Wo,
    const float* __restrict__ bo, float* __restrict__ out)
{
    const int gid  = blockIdx.x * 4 + (threadIdx.x >> 6);
    const int lane = threadIdx.x & 63;
    const int b = gid >> 10, o = gid & (H_ - 1);
    const float4* wr = (const float4*)(Wo + (size_t)o * H_);
    const float4* cr = (const float4*)(ctx + ((size_t)b << 10));
    float acc = 0.f;
    #pragma unroll
    for (int i = 0; i < 4; ++i) {
        float4 wv = wr[lane + i * 64];
        float4 cv = cr[lane + i * 64];
        acc += wv.x * cv.x + wv.y * cv.y + wv.z * cv.z + wv.w * cv.w;
    }
    #pragma unroll
    for (int off = 32; off; off >>= 1) acc += __shfl_xor(acc, off);
    if (lane == 0) out[(b << 10) + o] = acc * (1.0f / (float)L_) + bo[o];
}

__global__ void weights_kernel(const float* __restrict__ cs, float* __restrict__ out)
{
    int i = blockIdx.x * 256 + threadIdx.x;   // 8192
    int b = i >> 11, k = i & (L_ - 1);
    float s = 0.f;
    #pragma unroll
    for (int h = 0; h < NH_; ++h) s += cs[((size_t)(b * NH_ + h) << 11) + k];
    out[B_ * H_ + i] = s * (1.0f / (float)(NH_ * L_));
}

// ---------------------------------------------------------------------------
extern "C" void kernel_launch(void* const* d_in, const int* in_sizes, int n_in,
                              void* d_out, int out_size, void* d_ws, size_t ws_size,
                              hipStream_t stream)
{
    const float* x  = (const float*)d_in[0];
    const float* Wq = (const float*)d_in[1];
    const float* bq = (const float*)d_in[2];
    const float* Wk = (const float*)d_in[3];
    const float* bk = (const float*)d_in[4];
    const float* Wv = (const float*)d_in[5];
    const float* bv = (const float*)d_in[6];
    const float* Wo = (const float*)d_in[7];
    const float* bo = (const float*)d_in[8];
    float* out = (float*)d_out;

    float* ws  = (float*)d_ws;
    float* cs  = ws;                       // B*NH*L = 131072 f
    float* T   = ws + 131072;              // B*NH*H =  65536 f
    float* ctx = ws + 196608;              // B*H    =   4096 f
    ushort_t* base = (ushort_t*)(ws + 200704);
    const size_t QE = 8388608;             // B*NH*L*DK == B*L*H
    ushort_t* qhb = base;
    ushort_t* khb = base + QE;
    ushort_t* klb = base + 2 * QE;
    ushort_t* xhb = base + 3 * QE;
    ushort_t* xlb = base + 4 * QE;
    ushort_t* wqh = base + 5 * QE;
    ushort_t* wql = wqh + 1048576;
    ushort_t* wkh = wql + 1048576;
    ushort_t* wkl = wkh + 1048576;

    hipMemsetAsync(ws, 0, (131072 + 65536) * sizeof(float), stream);

    fsplit3_kernel<<<10240, 256, 0, stream>>>(x, Wq, Wk, xhb, xlb,
                                              wqh, wql, wkh, wkl);

    proj_split<<<dim3(8, 64, 2), 256, 0, stream>>>(xhb, xlb, wqh, wkh, wkl,
                                                   bq, bk, qhb, khb, klb);

    attn_split<<<B_ * NH_ * (L_ / 128), 256, 0, stream>>>(qhb, khb, klb, cs);

    ctx1_kernel<<<dim3(16, 4, 8), 256, 0, stream>>>(cs, x, T);
    ctx2_kernel<<<1024, 256, 0, stream>>>(T, Wv, bv, ctx);
    pooled_kernel<<<1024, 256, 0, stream>>>(ctx, Wo, bo, out);
    weights_kernel<<<(B_ * L_) / 256, 256, 0, stream>>>(cs, out);
}

// Round 10
// 357.554 us; speedup vs baseline: 1.0666x; 1.0666x over previous
//
#include <hip/hip_runtime.h>
#include <math.h>

#define B_  4
#define L_  2048
#define H_  1024
#define NH_ 16
#define DK_ 64

// 0.125 * log2(e): folded into q so attn scores are already in log2 units
#define QSC 0.18033688011112043f

typedef unsigned short ushort_t;
typedef __attribute__((ext_vector_type(8))) short short8;
typedef __attribute__((ext_vector_type(4))) float f32x4;

__device__ __forceinline__ ushort_t f2b(float f) {   // RNE fp32->bf16
    unsigned int u = __float_as_uint(f);
    return (ushort_t)((u + 0x7FFFu + ((u >> 16) & 1u)) >> 16);
}
__device__ __forceinline__ float b2f(ushort_t h) {
    return __uint_as_float(((unsigned int)h) << 16);
}
__device__ __forceinline__ float fexp2(float x) {
    return __builtin_amdgcn_exp2f(x);
}

__device__ __forceinline__ void gload_lds16(const void* g, void* l) {
    __builtin_amdgcn_global_load_lds((const __attribute__((address_space(1))) void*)g,
                                     (__attribute__((address_space(3))) void*)l, 16, 0, 0);
}

// ---------------------------------------------------------------------------
// RNE split cast for x, Wq, Wk in ONE launch + zero-fill of cs/T scratch.
// bid ranges: [0,8192) x | [8192,9216) Wq | [9216,10240) Wk | [10240,10432) zero
// ---------------------------------------------------------------------------
__global__ __launch_bounds__(256) void fsplit3_kernel(
    const float* __restrict__ x, const float* __restrict__ Wq, const float* __restrict__ Wk,
    ushort_t* __restrict__ xh, ushort_t* __restrict__ xl,
    ushort_t* __restrict__ wqh, ushort_t* __restrict__ wql,
    ushort_t* __restrict__ wkh, ushort_t* __restrict__ wkl,
    float* __restrict__ zero_dst)
{
    int bid = blockIdx.x;
    if (bid >= 10240) {
        int i = (bid - 10240) * 256 + threadIdx.x;     // 49152 float4 = 768 KB
        ((float4*)zero_dst)[i] = (float4){0.f, 0.f, 0.f, 0.f};
        return;
    }
    const float* src; ushort_t *ph, *pl; int i;
    if (bid < 8192)      { src = x;  ph = xh;  pl = xl;  i = bid * 256 + threadIdx.x; }
    else if (bid < 9216) { src = Wq; ph = wqh; pl = wql; i = (bid - 8192) * 256 + threadIdx.x; }
    else                 { src = Wk; ph = wkh; pl = wkl; i = (bid - 9216) * 256 + threadIdx.x; }
    float4 v = ((const float4*)src)[i];
    float f[4] = {v.x, v.y, v.z, v.w};
    ushort4 h, l;
    ushort_t hh[4], ll[4];
    #pragma unroll
    for (int e = 0; e < 4; ++e) {
        hh[e] = f2b(f[e]);
        ll[e] = f2b(f[e] - b2f(hh[e]));
    }
    h.x = hh[0]; h.y = hh[1]; h.z = hh[2]; h.w = hh[3];
    l.x = ll[0]; l.y = ll[1]; l.z = ll[2]; l.w = ll[3];
    ((ushort4*)ph)[i] = h;
    ((ushort4*)pl)[i] = l;
}

// ---------------------------------------------------------------------------
// Q/K projection from pre-split x planes. 128x128 tile, BK=32, 256 threads.
// z=0 (q): 2 MFMAs (ah+al)*Wh, output hi only, prescaled by QSC.
// z=1 (k): 3 MFMAs (al*Wh + ah*Wl + ah*Wh), output split (hi,lo).
// ---------------------------------------------------------------------------
__global__ __launch_bounds__(256) void proj_split(
    const ushort_t* __restrict__ xh, const ushort_t* __restrict__ xl,
    const ushort_t* __restrict__ Wqh,
    const ushort_t* __restrict__ Wkh, const ushort_t* __restrict__ Wkl,
    const float* __restrict__ bq, const float* __restrict__ bk,
    ushort_t* __restrict__ qho,
    ushort_t* __restrict__ kho, ushort_t* __restrict__ klo)
{
    const int z = blockIdx.z;
    const ushort_t* Wh = z ? Wkh : Wqh;
    const ushort_t* Wl = Wkl;
    const float* bias  = z ? bk  : bq;

    const int n0 = blockIdx.y * 128;
    const int o0 = blockIdx.x * 128;

    __shared__ ushort_t Ash[128 * 32];
    __shared__ ushort_t Asl[128 * 32];
    __shared__ ushort_t Bsh[128 * 32];
    __shared__ ushort_t Bsl[128 * 32];

    const int t = threadIdx.x;
    const int lane = t & 63, w = t >> 6;
    const int ln = lane & 15, qd = lane >> 4;
    const int wy = w >> 1, wx = w & 1;
    const int ldsbase = (t & ~63) * 8;

    int rowS[2], cS[2];
    #pragma unroll
    for (int i = 0; i < 2; ++i) {
        int slot = i * 256 + t;
        rowS[i] = slot >> 2;
        cS[i] = (slot & 3) ^ ((rowS[i] >> 1) & 3);
    }

    f32x4 acc[4][4];
    #pragma unroll
    for (int i = 0; i < 4; ++i)
        #pragma unroll
        for (int j = 0; j < 4; ++j) acc[i][j] = (f32x4){0.f, 0.f, 0.f, 0.f};

    for (int k0 = 0; k0 < H_; k0 += 32) {
        __syncthreads();
        #pragma unroll
        for (int i = 0; i < 2; ++i) {
            gload_lds16(xh + (size_t)(n0 + rowS[i]) * H_ + k0 + cS[i] * 8,
                        &Ash[i * 2048 + ldsbase]);
            gload_lds16(xl + (size_t)(n0 + rowS[i]) * H_ + k0 + cS[i] * 8,
                        &Asl[i * 2048 + ldsbase]);
            gload_lds16(Wh + (size_t)(o0 + rowS[i]) * H_ + k0 + cS[i] * 8,
                        &Bsh[i * 2048 + ldsbase]);
        }
        if (z) {
            #pragma unroll
            for (int i = 0; i < 2; ++i)
                gload_lds16(Wl + (size_t)(o0 + rowS[i]) * H_ + k0 + cS[i] * 8,
                            &Bsl[i * 2048 + ldsbase]);
        }
        __syncthreads();

        short8 bh4[4], bl4[4];
        #pragma unroll
        for (int nt = 0; nt < 4; ++nt) {
            int row = wx * 64 + nt * 16 + ln;
            int sz = (qd ^ ((row >> 1) & 3)) << 3;
            bh4[nt] = *(const short8*)&Bsh[row * 32 + sz];
            if (z) bl4[nt] = *(const short8*)&Bsl[row * 32 + sz];
        }
        #pragma unroll
        for (int mt = 0; mt < 4; ++mt) {
            int row = wy * 64 + mt * 16 + ln;
            int sz = (qd ^ ((row >> 1) & 3)) << 3;
            short8 ah = *(const short8*)&Ash[row * 32 + sz];
            short8 al = *(const short8*)&Asl[row * 32 + sz];
            if (z) {
                #pragma unroll
                for (int nt = 0; nt < 4; ++nt) {
                    acc[mt][nt] = __builtin_amdgcn_mfma_f32_16x16x32_bf16(al, bh4[nt], acc[mt][nt], 0, 0, 0);
                    acc[mt][nt] = __builtin_amdgcn_mfma_f32_16x16x32_bf16(ah, bl4[nt], acc[mt][nt], 0, 0, 0);
                    acc[mt][nt] = __builtin_amdgcn_mfma_f32_16x16x32_bf16(ah, bh4[nt], acc[mt][nt], 0, 0, 0);
                }
            } else {
                #pragma unroll
                for (int nt = 0; nt < 4; ++nt) {
                    acc[mt][nt] = __builtin_amdgcn_mfma_f32_16x16x32_bf16(al, bh4[nt], acc[mt][nt], 0, 0, 0);
                    acc[mt][nt] = __builtin_amdgcn_mfma_f32_16x16x32_bf16(ah, bh4[nt], acc[mt][nt], 0, 0, 0);
                }
            }
        }
    }

    #pragma unroll
    for (int nt = 0; nt < 4; ++nt) {
        int o = o0 + wx * 64 + nt * 16 + ln;
        float bvv = bias[o];
        int hh = o >> 6, d = o & 63;
        #pragma unroll
        for (int mt = 0; mt < 4; ++mt) {
            #pragma unroll
            for (int r = 0; r < 4; ++r) {
                int n = n0 + wy * 64 + mt * 16 + qd * 4 + r;
                int bb = n >> 11, l = n & (L_ - 1);
                size_t idx = (((size_t)(bb * NH_ + hh) * L_ + l) << 6) + d;
                float val = acc[mt][nt][r] + bvv;
                if (z) {
                    ushort_t vh = f2b(val);
                    kho[idx] = vh;
                    klo[idx] = f2b(val - b2f(vh));
                } else {
                    qho[idx] = f2b(val * QSC);
                }
            }
        }
    }
}

// ---------------------------------------------------------------------------
// Attention column sums cs[b,h,k] = sum_q P[q,k]. q-tile 128/block, 2 A-sets
// per wave (R8-proven structure: single-buffer staging, LDS block reduction).
// pass1: qh*kh denominators. pass2: qh*(kh+kl) numerators.
// ---------------------------------------------------------------------------
__global__ __launch_bounds__(256) void attn_split(
    const ushort_t* __restrict__ qh,
    const ushort_t* __restrict__ kh, const ushort_t* __restrict__ kl,
    float* __restrict__ cs)
{
    const int qt = blockIdx.x & 15;        // 16 q-tiles of 128 rows
    const int bh = blockIdx.x >> 4;

    const int t = threadIdx.x;
    const int lane = t & 63, w = t >> 6;
    const int ln = lane & 15, qd = lane >> 4;

    __shared__ ushort_t Ksh[64 * 64];
    __shared__ ushort_t Ksl[64 * 64];
    __shared__ float cs_all[4][64];

    const size_t headoff = (size_t)bh * L_ * DK_;
    const size_t qoff0 = headoff + ((size_t)(qt * 128 + w * 32 + ln)) * DK_;
    const size_t qoff1 = qoff0 + 16 * DK_;
    short8 aqh[2][2];
    aqh[0][0] = *(const short8*)(qh + qoff0 + qd * 8);
    aqh[0][1] = *(const short8*)(qh + qoff0 + 32 + qd * 8);
    aqh[1][0] = *(const short8*)(qh + qoff1 + qd * 8);
    aqh[1][1] = *(const short8*)(qh + qoff1 + 32 + qd * 8);

    int rowS[2], cS[2];
    #pragma unroll
    for (int i = 0; i < 2; ++i) {
        int slot = i * 256 + t;
        rowS[i] = slot >> 3;
        cS[i] = (slot & 7) ^ (rowS[i] & 7);
    }

    float l_run[2][4] = {};

    // ---------------- pass 1: l = sum_k exp2(s_hi) ----------------
    for (int kt = 0; kt < 32; ++kt) {
        __syncthreads();
        #pragma unroll
        for (int i = 0; i < 2; ++i)
            gload_lds16(kh + headoff + ((size_t)(kt * 64 + rowS[i]) << 6) + cS[i] * 8,
                        &Ksh[i * 2048 + (t & ~63) * 8]);
        __syncthreads();

        #pragma unroll
        for (int nt = 0; nt < 4; ++nt) {
            int kr = nt * 16 + ln;
            int sz0 = ((qd     ^ (kr & 7)) << 3);
            int sz1 = (((qd + 4) ^ (kr & 7)) << 3);
            short8 b0h = *(const short8*)&Ksh[kr * 64 + sz0];
            short8 b1h = *(const short8*)&Ksh[kr * 64 + sz1];
            #pragma unroll
            for (int s = 0; s < 2; ++s) {
                f32x4 zz = (f32x4){0.f, 0.f, 0.f, 0.f};
                zz = __builtin_amdgcn_mfma_f32_16x16x32_bf16(aqh[s][0], b0h, zz, 0, 0, 0);
                zz = __builtin_amdgcn_mfma_f32_16x16x32_bf16(aqh[s][1], b1h, zz, 0, 0, 0);
                #pragma unroll
                for (int r = 0; r < 4; ++r)
                    l_run[s][r] += fexp2(zz[r]);
            }
        }
    }

    #pragma unroll
    for (int off = 1; off < 16; off <<= 1)
        #pragma unroll
        for (int s = 0; s < 2; ++s)
            #pragma unroll
            for (int r = 0; r < 4; ++r)
                l_run[s][r] += __shfl_xor(l_run[s][r], off);
    float inv_l[2][4];
    #pragma unroll
    for (int s = 0; s < 2; ++s)
        #pragma unroll
        for (int r = 0; r < 4; ++r) inv_l[s][r] = 1.0f / l_run[s][r];

    // ---------------- pass 2: column sums (k split, q hi) ----------------
    for (int kt = 0; kt < 32; ++kt) {
        __syncthreads();
        #pragma unroll
        for (int i = 0; i < 2; ++i) {
            gload_lds16(kh + headoff + ((size_t)(kt * 64 + rowS[i]) << 6) + cS[i] * 8,
                        &Ksh[i * 2048 + (t & ~63) * 8]);
            gload_lds16(kl + headoff + ((size_t)(kt * 64 + rowS[i]) << 6) + cS[i] * 8,
                        &Ksl[i * 2048 + (t & ~63) * 8]);
        }
        __syncthreads();

        float colp[4];
        #pragma unroll
        for (int nt = 0; nt < 4; ++nt) {
            int kr = nt * 16 + ln;
            int sz0 = ((qd     ^ (kr & 7)) << 3);
            int sz1 = (((qd + 4) ^ (kr & 7)) << 3);
            short8 b0h = *(const short8*)&Ksh[kr * 64 + sz0];
            short8 b1h = *(const short8*)&Ksh[kr * 64 + sz1];
            short8 b0l = *(const short8*)&Ksl[kr * 64 + sz0];
            short8 b1l = *(const short8*)&Ksl[kr * 64 + sz1];
            float cp = 0.f;
            #pragma unroll
            for (int s = 0; s < 2; ++s) {
                f32x4 zz = (f32x4){0.f, 0.f, 0.f, 0.f};
                zz = __builtin_amdgcn_mfma_f32_16x16x32_bf16(aqh[s][0], b0l, zz, 0, 0, 0);
                zz = __builtin_amdgcn_mfma_f32_16x16x32_bf16(aqh[s][1], b1l, zz, 0, 0, 0);
                zz = __builtin_amdgcn_mfma_f32_16x16x32_bf16(aqh[s][0], b0h, zz, 0, 0, 0);
                zz = __builtin_amdgcn_mfma_f32_16x16x32_bf16(aqh[s][1], b1h, zz, 0, 0, 0);
                cp += fexp2(zz[0]) * inv_l[s][0] + fexp2(zz[1]) * inv_l[s][1]
                    + fexp2(zz[2]) * inv_l[s][2] + fexp2(zz[3]) * inv_l[s][3];
            }
            colp[nt] = cp;
        }
        #pragma unroll
        for (int nt = 0; nt < 4; ++nt) {
            colp[nt] += __shfl_xor(colp[nt], 16);
            colp[nt] += __shfl_xor(colp[nt], 32);
        }
        float mine = (qd == 0) ? colp[0] : (qd == 1) ? colp[1] : (qd == 2) ? colp[2] : colp[3];
        cs_all[w][lane] = mine;
        __syncthreads();
        if (t < 64) {
            float tot = cs_all[0][t] + cs_all[1][t] + cs_all[2][t] + cs_all[3][t];
            atomicAdd(&cs[(size_t)bh * L_ + kt * 64 + t], tot);
        }
    }
}

// ---------------------------------------------------------------------------
// T[b,h,h'] = sum_l cs[b,h,l] * x[b,l,h']  (fp32, atomic over 8 l-splits)
// + blocks with o-chunk 0 also emit weights[b,l] = sum_h cs[b,h,l]/(NH*L)
// ---------------------------------------------------------------------------
__global__ __launch_bounds__(256) void ctx1_kernel(
    const float* __restrict__ cs, const float* __restrict__ x,
    float* __restrict__ T, float* __restrict__ out)
{
    const int o0 = blockIdx.x * 64, b = blockIdx.y, l0 = blockIdx.z * 256;
    const int t = threadIdx.x, o = t & 63, hg = t >> 6;
    __shared__ float cs_s[16][128];
    float acc[4] = {};

    for (int ch = 0; ch < 2; ++ch) {
        int lbase = l0 + ch * 128;
        __syncthreads();
        for (int i = t; i < 2048; i += 256) {
            int h = i >> 7, lc = i & 127;
            cs_s[h][lc] = cs[((size_t)(b * NH_ + h) << 11) + lbase + lc];
        }
        __syncthreads();
        if (blockIdx.x == 0 && t < 128) {      // weights fused here
            float s = 0.f;
            #pragma unroll
            for (int h = 0; h < NH_; ++h) s += cs_s[h][t];
            out[B_ * H_ + b * L_ + lbase + t] = s * (1.0f / (float)(NH_ * L_));
        }
        for (int lc = 0; lc < 128; ++lc) {
            float xv = x[((size_t)(b * L_ + lbase + lc) << 10) + o0 + o];
            #pragma unroll
            for (int j = 0; j < 4; ++j) acc[j] += cs_s[hg * 4 + j][lc] * xv;
        }
    }
    #pragma unroll
    for (int j = 0; j < 4; ++j)
        atomicAdd(&T[((size_t)(b * NH_ + hg * 4 + j) << 10) + o0 + o], acc[j]);
}

// ---------------------------------------------------------------------------
// ctx[b,o] = sum_h' T[b, o>>6, h'] * Wv[o,h'] + L*bv[o]; wave per row
// ---------------------------------------------------------------------------
__global__ __launch_bounds__(256) void ctx2_kernel(
    const float* __restrict__ T, const float* __restrict__ Wv,
    const float* __restrict__ bv, float* __restrict__ ctx)
{
    const int gid  = blockIdx.x * 4 + (threadIdx.x >> 6);
    const int lane = threadIdx.x & 63;
    const int b = gid >> 10, o = gid & (H_ - 1);
    const float4* wr = (const float4*)(Wv + (size_t)o * H_);
    const float4* tr = (const float4*)(T + ((size_t)(b * NH_ + (o >> 6)) << 10));
    float acc = 0.f;
    #pragma unroll
    for (int i = 0; i < 4; ++i) {
        float4 wv = wr[lane + i * 64];
        float4 tv = tr[lane + i * 64];
        acc += wv.x * tv.x + wv.y * tv.y + wv.z * tv.z + wv.w * tv.w;
    }
    #pragma unroll
    for (int off = 32; off; off >>= 1) acc += __shfl_xor(acc, off);
    if (lane == 0) ctx[(b << 10) + o] = acc + (float)L_ * bv[o];
}

// ---------------------------------------------------------------------------
// pooled[b,o] = bo[o] + (1/L) * sum_h ctx[b,h] * Wo[o,h]; wave per row
// ---------------------------------------------------------------------------
__global__ __launch_bounds__(256) void pooled_kernel(
    const float* __restrict__ ctx, const float* __restrict__ Wo,
    const float* __restrict__ bo, float* __restrict__ out)
{
    const int gid  = blockIdx.x * 4 + (threadIdx.x >> 6);
    const int lane = threadIdx.x & 63;
    const int b = gid >> 10, o = gid & (H_ - 1);
    const float4* wr = (const float4*)(Wo + (size_t)o * H_);
    const float4* cr = (const float4*)(ctx + ((size_t)b << 10));
    float acc = 0.f;
    #pragma unroll
    for (int i = 0; i < 4; ++i) {
        float4 wv = wr[lane + i * 64];
        float4 cv = cr[lane + i * 64];
        acc += wv.x * cv.x + wv.y * cv.y + wv.z * cv.z + wv.w * cv.w;
    }
    #pragma unroll
    for (int off = 32; off; off >>= 1) acc += __shfl_xor(acc, off);
    if (lane == 0) out[(b << 10) + o] = acc * (1.0f / (float)L_) + bo[o];
}

// ---------------------------------------------------------------------------
extern "C" void kernel_launch(void* const* d_in, const int* in_sizes, int n_in,
                              void* d_out, int out_size, void* d_ws, size_t ws_size,
                              hipStream_t stream)
{
    const float* x  = (const float*)d_in[0];
    const float* Wq = (const float*)d_in[1];
    const float* bq = (const float*)d_in[2];
    const float* Wk = (const float*)d_in[3];
    const float* bk = (const float*)d_in[4];
    const float* Wv = (const float*)d_in[5];
    const float* bv = (const float*)d_in[6];
    const float* Wo = (const float*)d_in[7];
    const float* bo = (const float*)d_in[8];
    float* out = (float*)d_out;

    float* ws  = (float*)d_ws;
    float* cs  = ws;                       // B*NH*L = 131072 f
    float* T   = ws + 131072;              // B*NH*H =  65536 f
    float* ctx = ws + 196608;              // B*H    =   4096 f
    ushort_t* base = (ushort_t*)(ws + 200704);
    const size_t QE = 8388608;             // B*NH*L*DK == B*L*H
    ushort_t* qhb = base;
    ushort_t* khb = base + QE;
    ushort_t* klb = base + 2 * QE;
    ushort_t* xhb = base + 3 * QE;
    ushort_t* xlb = base + 4 * QE;
    ushort_t* wqh = base + 5 * QE;
    ushort_t* wql = wqh + 1048576;
    ushort_t* wkh = wql + 1048576;
    ushort_t* wkl = wkh + 1048576;

    // fsplit3 also zeroes cs+T (first 196608 floats of ws)
    fsplit3_kernel<<<10432, 256, 0, stream>>>(x, Wq, Wk, xhb, xlb,
                                              wqh, wql, wkh, wkl, ws);

    proj_split<<<dim3(8, 64, 2), 256, 0, stream>>>(xhb, xlb, wqh, wkh, wkl,
                                                   bq, bk, qhb, khb, klb);

    attn_split<<<B_ * NH_ * (L_ / 128), 256, 0, stream>>>(qhb, khb, klb, cs);

    ctx1_kernel<<<dim3(16, 4, 8), 256, 0, stream>>>(cs, x, T, out);
    ctx2_kernel<<<1024, 256, 0, stream>>>(T, Wv, bv, ctx);
    pooled_kernel<<<1024, 256, 0, stream>>>(ctx, Wo, bo, out);
}

// Round 11
// 345.208 us; speedup vs baseline: 1.1047x; 1.0358x over previous
//
#include <hip/hip_runtime.h>
#include <math.h>

#define B_  4
#define L_  2048
#define H_  1024
#define NH_ 16
#define DK_ 64

// 0.125 * log2(e): folded into q so attn scores are already in log2 units
#define QSC 0.18033688011112043f

typedef unsigned short ushort_t;
typedef __attribute__((ext_vector_type(8))) short short8;
typedef __attribute__((ext_vector_type(4))) float f32x4;

__device__ __forceinline__ ushort_t f2b(float f) {   // RNE fp32->bf16
    unsigned int u = __float_as_uint(f);
    return (ushort_t)((u + 0x7FFFu + ((u >> 16) & 1u)) >> 16);
}
__device__ __forceinline__ float b2f(ushort_t h) {
    return __uint_as_float(((unsigned int)h) << 16);
}
__device__ __forceinline__ float fexp2(float x) {
    return __builtin_amdgcn_exp2f(x);
}

__device__ __forceinline__ void gload_lds16(const void* g, void* l) {
    __builtin_amdgcn_global_load_lds((const __attribute__((address_space(1))) void*)g,
                                     (__attribute__((address_space(3))) void*)l, 16, 0, 0);
}

// ---------------------------------------------------------------------------
// RNE split cast for x, Wk (hi+lo) and Wq (hi only) + zero-fill of cs/T.
// bid: [0,8192) x | [8192,9216) Wq(hi) | [9216,10240) Wk | [10240,10432) zero
// ---------------------------------------------------------------------------
__global__ __launch_bounds__(256) void fsplit3_kernel(
    const float* __restrict__ x, const float* __restrict__ Wq, const float* __restrict__ Wk,
    ushort_t* __restrict__ xh, ushort_t* __restrict__ xl,
    ushort_t* __restrict__ wqh,
    ushort_t* __restrict__ wkh, ushort_t* __restrict__ wkl,
    float* __restrict__ zero_dst)
{
    int bid = blockIdx.x;
    if (bid >= 10240) {
        int i = (bid - 10240) * 256 + threadIdx.x;     // 49152 float4 = 768 KB
        ((float4*)zero_dst)[i] = (float4){0.f, 0.f, 0.f, 0.f};
        return;
    }
    if (bid >= 8192 && bid < 9216) {                   // Wq: hi plane only
        int i = (bid - 8192) * 256 + threadIdx.x;
        float4 v = ((const float4*)Wq)[i];
        ushort4 h;
        h.x = f2b(v.x); h.y = f2b(v.y); h.z = f2b(v.z); h.w = f2b(v.w);
        ((ushort4*)wqh)[i] = h;
        return;
    }
    const float* src; ushort_t *ph, *pl; int i;
    if (bid < 8192) { src = x;  ph = xh;  pl = xl;  i = bid * 256 + threadIdx.x; }
    else            { src = Wk; ph = wkh; pl = wkl; i = (bid - 9216) * 256 + threadIdx.x; }
    float4 v = ((const float4*)src)[i];
    float f[4] = {v.x, v.y, v.z, v.w};
    ushort4 h, l;
    ushort_t hh[4], ll[4];
    #pragma unroll
    for (int e = 0; e < 4; ++e) {
        hh[e] = f2b(f[e]);
        ll[e] = f2b(f[e] - b2f(hh[e]));
    }
    h.x = hh[0]; h.y = hh[1]; h.z = hh[2]; h.w = hh[3];
    l.x = ll[0]; l.y = ll[1]; l.z = ll[2]; l.w = ll[3];
    ((ushort4*)ph)[i] = h;
    ((ushort4*)pl)[i] = l;
}

// ---------------------------------------------------------------------------
// Q/K projection. 128x128 tile, BK=32, 256 threads.
// z=0 (q): 1 MFMA ah*Wh (q is stored bf16 anyway — storage rounding
//          dominates, dropped al*Wh is per-row noise that averages out).
// z=1 (k): 3 MFMAs (al*Wh + ah*Wl + ah*Wh), output split (hi,lo) — k-side
//          errors are systematic across q and must stay ~2^-17.
// ---------------------------------------------------------------------------
__global__ __launch_bounds__(256) void proj_split(
    const ushort_t* __restrict__ xh, const ushort_t* __restrict__ xl,
    const ushort_t* __restrict__ Wqh,
    const ushort_t* __restrict__ Wkh, const ushort_t* __restrict__ Wkl,
    const float* __restrict__ bq, const float* __restrict__ bk,
    ushort_t* __restrict__ qho,
    ushort_t* __restrict__ kho, ushort_t* __restrict__ klo)
{
    const int z = blockIdx.z;
    const ushort_t* Wh = z ? Wkh : Wqh;
    const ushort_t* Wl = Wkl;
    const float* bias  = z ? bk  : bq;

    const int n0 = blockIdx.y * 128;
    const int o0 = blockIdx.x * 128;

    __shared__ ushort_t Ash[128 * 32];
    __shared__ ushort_t Asl[128 * 32];
    __shared__ ushort_t Bsh[128 * 32];
    __shared__ ushort_t Bsl[128 * 32];

    const int t = threadIdx.x;
    const int lane = t & 63, w = t >> 6;
    const int ln = lane & 15, qd = lane >> 4;
    const int wy = w >> 1, wx = w & 1;
    const int ldsbase = (t & ~63) * 8;

    int rowS[2], cS[2];
    #pragma unroll
    for (int i = 0; i < 2; ++i) {
        int slot = i * 256 + t;
        rowS[i] = slot >> 2;
        cS[i] = (slot & 3) ^ ((rowS[i] >> 1) & 3);
    }

    f32x4 acc[4][4];
    #pragma unroll
    for (int i = 0; i < 4; ++i)
        #pragma unroll
        for (int j = 0; j < 4; ++j) acc[i][j] = (f32x4){0.f, 0.f, 0.f, 0.f};

    for (int k0 = 0; k0 < H_; k0 += 32) {
        __syncthreads();
        #pragma unroll
        for (int i = 0; i < 2; ++i) {
            gload_lds16(xh + (size_t)(n0 + rowS[i]) * H_ + k0 + cS[i] * 8,
                        &Ash[i * 2048 + ldsbase]);
            gload_lds16(Wh + (size_t)(o0 + rowS[i]) * H_ + k0 + cS[i] * 8,
                        &Bsh[i * 2048 + ldsbase]);
        }
        if (z) {
            #pragma unroll
            for (int i = 0; i < 2; ++i) {
                gload_lds16(xl + (size_t)(n0 + rowS[i]) * H_ + k0 + cS[i] * 8,
                            &Asl[i * 2048 + ldsbase]);
                gload_lds16(Wl + (size_t)(o0 + rowS[i]) * H_ + k0 + cS[i] * 8,
                            &Bsl[i * 2048 + ldsbase]);
            }
        }
        __syncthreads();

        short8 bh4[4], bl4[4];
        #pragma unroll
        for (int nt = 0; nt < 4; ++nt) {
            int row = wx * 64 + nt * 16 + ln;
            int sz = (qd ^ ((row >> 1) & 3)) << 3;
            bh4[nt] = *(const short8*)&Bsh[row * 32 + sz];
            if (z) bl4[nt] = *(const short8*)&Bsl[row * 32 + sz];
        }
        #pragma unroll
        for (int mt = 0; mt < 4; ++mt) {
            int row = wy * 64 + mt * 16 + ln;
            int sz = (qd ^ ((row >> 1) & 3)) << 3;
            short8 ah = *(const short8*)&Ash[row * 32 + sz];
            if (z) {
                short8 al = *(const short8*)&Asl[row * 32 + sz];
                #pragma unroll
                for (int nt = 0; nt < 4; ++nt) {
                    acc[mt][nt] = __builtin_amdgcn_mfma_f32_16x16x32_bf16(al, bh4[nt], acc[mt][nt], 0, 0, 0);
                    acc[mt][nt] = __builtin_amdgcn_mfma_f32_16x16x32_bf16(ah, bl4[nt], acc[mt][nt], 0, 0, 0);
                    acc[mt][nt] = __builtin_amdgcn_mfma_f32_16x16x32_bf16(ah, bh4[nt], acc[mt][nt], 0, 0, 0);
                }
            } else {
                #pragma unroll
                for (int nt = 0; nt < 4; ++nt)
                    acc[mt][nt] = __builtin_amdgcn_mfma_f32_16x16x32_bf16(ah, bh4[nt], acc[mt][nt], 0, 0, 0);
            }
        }
    }

    #pragma unroll
    for (int nt = 0; nt < 4; ++nt) {
        int o = o0 + wx * 64 + nt * 16 + ln;
        float bvv = bias[o];
        int hh = o >> 6, d = o & 63;
        #pragma unroll
        for (int mt = 0; mt < 4; ++mt) {
            #pragma unroll
            for (int r = 0; r < 4; ++r) {
                int n = n0 + wy * 64 + mt * 16 + qd * 4 + r;
                int bb = n >> 11, l = n & (L_ - 1);
                size_t idx = (((size_t)(bb * NH_ + hh) * L_ + l) << 6) + d;
                float val = acc[mt][nt][r] + bvv;
                if (z) {
                    ushort_t vh = f2b(val);
                    kho[idx] = vh;
                    klo[idx] = f2b(val - b2f(vh));
                } else {
                    qho[idx] = f2b(val * QSC);
                }
            }
        }
    }
}

// ---------------------------------------------------------------------------
// Attention column sums cs[b,h,k] = sum_q P[q,k]. q-tile 128/block, 2 A-sets
// per wave (R8-proven structure: single-buffer staging, LDS block reduction).
// pass1: qh*kh denominators. pass2: qh*(kh+kl) numerators.
// ---------------------------------------------------------------------------
__global__ __launch_bounds__(256) void attn_split(
    const ushort_t* __restrict__ qh,
    const ushort_t* __restrict__ kh, const ushort_t* __restrict__ kl,
    float* __restrict__ cs)
{
    const int qt = blockIdx.x & 15;        // 16 q-tiles of 128 rows
    const int bh = blockIdx.x >> 4;

    const int t = threadIdx.x;
    const int lane = t & 63, w = t >> 6;
    const int ln = lane & 15, qd = lane >> 4;

    __shared__ ushort_t Ksh[64 * 64];
    __shared__ ushort_t Ksl[64 * 64];
    __shared__ float cs_all[4][64];

    const size_t headoff = (size_t)bh * L_ * DK_;
    const size_t qoff0 = headoff + ((size_t)(qt * 128 + w * 32 + ln)) * DK_;
    const size_t qoff1 = qoff0 + 16 * DK_;
    short8 aqh[2][2];
    aqh[0][0] = *(const short8*)(qh + qoff0 + qd * 8);
    aqh[0][1] = *(const short8*)(qh + qoff0 + 32 + qd * 8);
    aqh[1][0] = *(const short8*)(qh + qoff1 + qd * 8);
    aqh[1][1] = *(const short8*)(qh + qoff1 + 32 + qd * 8);

    int rowS[2], cS[2];
    #pragma unroll
    for (int i = 0; i < 2; ++i) {
        int slot = i * 256 + t;
        rowS[i] = slot >> 3;
        cS[i] = (slot & 7) ^ (rowS[i] & 7);
    }

    float l_run[2][4] = {};

    // ---------------- pass 1: l = sum_k exp2(s_hi) ----------------
    for (int kt = 0; kt < 32; ++kt) {
        __syncthreads();
        #pragma unroll
        for (int i = 0; i < 2; ++i)
            gload_lds16(kh + headoff + ((size_t)(kt * 64 + rowS[i]) << 6) + cS[i] * 8,
                        &Ksh[i * 2048 + (t & ~63) * 8]);
        __syncthreads();

        #pragma unroll
        for (int nt = 0; nt < 4; ++nt) {
            int kr = nt * 16 + ln;
            int sz0 = ((qd     ^ (kr & 7)) << 3);
            int sz1 = (((qd + 4) ^ (kr & 7)) << 3);
            short8 b0h = *(const short8*)&Ksh[kr * 64 + sz0];
            short8 b1h = *(const short8*)&Ksh[kr * 64 + sz1];
            #pragma unroll
            for (int s = 0; s < 2; ++s) {
                f32x4 zz = (f32x4){0.f, 0.f, 0.f, 0.f};
                zz = __builtin_amdgcn_mfma_f32_16x16x32_bf16(aqh[s][0], b0h, zz, 0, 0, 0);
                zz = __builtin_amdgcn_mfma_f32_16x16x32_bf16(aqh[s][1], b1h, zz, 0, 0, 0);
                #pragma unroll
                for (int r = 0; r < 4; ++r)
                    l_run[s][r] += fexp2(zz[r]);
            }
        }
    }

    #pragma unroll
    for (int off = 1; off < 16; off <<= 1)
        #pragma unroll
        for (int s = 0; s < 2; ++s)
            #pragma unroll
            for (int r = 0; r < 4; ++r)
                l_run[s][r] += __shfl_xor(l_run[s][r], off);
    float inv_l[2][4];
    #pragma unroll
    for (int s = 0; s < 2; ++s)
        #pragma unroll
        for (int r = 0; r < 4; ++r) inv_l[s][r] = 1.0f / l_run[s][r];

    // ---------------- pass 2: column sums (k split, q hi) ----------------
    for (int kt = 0; kt < 32; ++kt) {
        __syncthreads();
        #pragma unroll
        for (int i = 0; i < 2; ++i) {
            gload_lds16(kh + headoff + ((size_t)(kt * 64 + rowS[i]) << 6) + cS[i] * 8,
                        &Ksh[i * 2048 + (t & ~63) * 8]);
            gload_lds16(kl + headoff + ((size_t)(kt * 64 + rowS[i]) << 6) + cS[i] * 8,
                        &Ksl[i * 2048 + (t & ~63) * 8]);
        }
        __syncthreads();

        float colp[4];
        #pragma unroll
        for (int nt = 0; nt < 4; ++nt) {
            int kr = nt * 16 + ln;
            int sz0 = ((qd     ^ (kr & 7)) << 3);
            int sz1 = (((qd + 4) ^ (kr & 7)) << 3);
            short8 b0h = *(const short8*)&Ksh[kr * 64 + sz0];
            short8 b1h = *(const short8*)&Ksh[kr * 64 + sz1];
            short8 b0l = *(const short8*)&Ksl[kr * 64 + sz0];
            short8 b1l = *(const short8*)&Ksl[kr * 64 + sz1];
            float cp = 0.f;
            #pragma unroll
            for (int s = 0; s < 2; ++s) {
                f32x4 zz = (f32x4){0.f, 0.f, 0.f, 0.f};
                zz = __builtin_amdgcn_mfma_f32_16x16x32_bf16(aqh[s][0], b0l, zz, 0, 0, 0);
                zz = __builtin_amdgcn_mfma_f32_16x16x32_bf16(aqh[s][1], b1l, zz, 0, 0, 0);
                zz = __builtin_amdgcn_mfma_f32_16x16x32_bf16(aqh[s][0], b0h, zz, 0, 0, 0);
                zz = __builtin_amdgcn_mfma_f32_16x16x32_bf16(aqh[s][1], b1h, zz, 0, 0, 0);
                cp += fexp2(zz[0]) * inv_l[s][0] + fexp2(zz[1]) * inv_l[s][1]
                    + fexp2(zz[2]) * inv_l[s][2] + fexp2(zz[3]) * inv_l[s][3];
            }
            colp[nt] = cp;
        }
        #pragma unroll
        for (int nt = 0; nt < 4; ++nt) {
            colp[nt] += __shfl_xor(colp[nt], 16);
            colp[nt] += __shfl_xor(colp[nt], 32);
        }
        float mine = (qd == 0) ? colp[0] : (qd == 1) ? colp[1] : (qd == 2) ? colp[2] : colp[3];
        cs_all[w][lane] = mine;
        __syncthreads();
        if (t < 64) {
            float tot = cs_all[0][t] + cs_all[1][t] + cs_all[2][t] + cs_all[3][t];
            atomicAdd(&cs[(size_t)bh * L_ + kt * 64 + t], tot);
        }
    }
}

// ---------------------------------------------------------------------------
// T[b,h,h'] = sum_l cs[b,h,l] * x[b,l,h']  (fp32, atomic over 8 l-splits)
// + blocks with o-chunk 0 also emit weights[b,l] = sum_h cs[b,h,l]/(NH*L)
// ---------------------------------------------------------------------------
__global__ __launch_bounds__(256) void ctx1_kernel(
    const float* __restrict__ cs, const float* __restrict__ x,
    float* __restrict__ T, float* __restrict__ out)
{
    const int o0 = blockIdx.x * 64, b = blockIdx.y, l0 = blockIdx.z * 256;
    const int t = threadIdx.x, o = t & 63, hg = t >> 6;
    __shared__ float cs_s[16][128];
    float acc[4] = {};

    for (int ch = 0; ch < 2; ++ch) {
        int lbase = l0 + ch * 128;
        __syncthreads();
        for (int i = t; i < 2048; i += 256) {
            int h = i >> 7, lc = i & 127;
            cs_s[h][lc] = cs[((size_t)(b * NH_ + h) << 11) + lbase + lc];
        }
        __syncthreads();
        if (blockIdx.x == 0 && t < 128) {      // weights fused here
            float s = 0.f;
            #pragma unroll
            for (int h = 0; h < NH_; ++h) s += cs_s[h][t];
            out[B_ * H_ + b * L_ + lbase + t] = s * (1.0f / (float)(NH_ * L_));
        }
        for (int lc = 0; lc < 128; ++lc) {
            float xv = x[((size_t)(b * L_ + lbase + lc) << 10) + o0 + o];
            #pragma unroll
            for (int j = 0; j < 4; ++j) acc[j] += cs_s[hg * 4 + j][lc] * xv;
        }
    }
    #pragma unroll
    for (int j = 0; j < 4; ++j)
        atomicAdd(&T[((size_t)(b * NH_ + hg * 4 + j) << 10) + o0 + o], acc[j]);
}

// ---------------------------------------------------------------------------
// ctx[b,o] = sum_h' T[b, o>>6, h'] * Wv[o,h'] + L*bv[o]; wave per row
// ---------------------------------------------------------------------------
__global__ __launch_bounds__(256) void ctx2_kernel(
    const float* __restrict__ T, const float* __restrict__ Wv,
    const float* __restrict__ bv, float* __restrict__ ctx)
{
    const int gid  = blockIdx.x * 4 + (threadIdx.x >> 6);
    const int lane = threadIdx.x & 63;
    const int b = gid >> 10, o = gid & (H_ - 1);
    const float4* wr = (const float4*)(Wv + (size_t)o * H_);
    const float4* tr = (const float4*)(T + ((size_t)(b * NH_ + (o >> 6)) << 10));
    float acc = 0.f;
    #pragma unroll
    for (int i = 0; i < 4; ++i) {
        float4 wv = wr[lane + i * 64];
        float4 tv = tr[lane + i * 64];
        acc += wv.x * tv.x + wv.y * tv.y + wv.z * tv.z + wv.w * tv.w;
    }
    #pragma unroll
    for (int off = 32; off; off >>= 1) acc += __shfl_xor(acc, off);
    if (lane == 0) ctx[(b << 10) + o] = acc + (float)L_ * bv[o];
}

// ---------------------------------------------------------------------------
// pooled[b,o] = bo[o] + (1/L) * sum_h ctx[b,h] * Wo[o,h]; wave per row
// ---------------------------------------------------------------------------
__global__ __launch_bounds__(256) void pooled_kernel(
    const float* __restrict__ ctx, const float* __restrict__ Wo,
    const float* __restrict__ bo, float* __restrict__ out)
{
    const int gid  = blockIdx.x * 4 + (threadIdx.x >> 6);
    const int lane = threadIdx.x & 63;
    const int b = gid >> 10, o = gid & (H_ - 1);
    const float4* wr = (const float4*)(Wo + (size_t)o * H_);
    const float4* cr = (const float4*)(ctx + ((size_t)b << 10));
    float acc = 0.f;
    #pragma unroll
    for (int i = 0; i < 4; ++i) {
        float4 wv = wr[lane + i * 64];
        float4 cv = cr[lane + i * 64];
        acc += wv.x * cv.x + wv.y * cv.y + wv.z * cv.z + wv.w * cv.w;
    }
    #pragma unroll
    for (int off = 32; off; off >>= 1) acc += __shfl_xor(acc, off);
    if (lane == 0) out[(b << 10) + o] = acc * (1.0f / (float)L_) + bo[o];
}

// ---------------------------------------------------------------------------
extern "C" void kernel_launch(void* const* d_in, const int* in_sizes, int n_in,
                              void* d_out, int out_size, void* d_ws, size_t ws_size,
                              hipStream_t stream)
{
    const float* x  = (const float*)d_in[0];
    const float* Wq = (const float*)d_in[1];
    const float* bq = (const float*)d_in[2];
    const float* Wk = (const float*)d_in[3];
    const float* bk = (const float*)d_in[4];
    const float* Wv = (const float*)d_in[5];
    const float* bv = (const float*)d_in[6];
    const float* Wo = (const float*)d_in[7];
    const float* bo = (const float*)d_in[8];
    float* out = (float*)d_out;

    float* ws  = (float*)d_ws;
    float* cs  = ws;                       // B*NH*L = 131072 f
    float* T   = ws + 131072;              // B*NH*H =  65536 f
    float* ctx = ws + 196608;              // B*H    =   4096 f
    ushort_t* base = (ushort_t*)(ws + 200704);
    const size_t QE = 8388608;             // B*NH*L*DK == B*L*H
    ushort_t* qhb = base;
    ushort_t* khb = base + QE;
    ushort_t* klb = base + 2 * QE;
    ushort_t* xhb = base + 3 * QE;
    ushort_t* xlb = base + 4 * QE;
    ushort_t* wqh = base + 5 * QE;
    ushort_t* wkh = wqh + 1048576;
    ushort_t* wkl = wkh + 1048576;

    // fsplit3 also zeroes cs+T (first 196608 floats of ws)
    fsplit3_kernel<<<10432, 256, 0, stream>>>(x, Wq, Wk, xhb, xlb,
                                              wqh, wkh, wkl, ws);

    proj_split<<<dim3(8, 64, 2), 256, 0, stream>>>(xhb, xlb, wqh, wkh, wkl,
                                                   bq, bk, qhb, khb, klb);

    attn_split<<<B_ * NH_ * (L_ / 128), 256, 0, stream>>>(qhb, khb, klb, cs);

    ctx1_kernel<<<dim3(16, 4, 8), 256, 0, stream>>>(cs, x, T, out);
    ctx2_kernel<<<1024, 256, 0, stream>>>(T, Wv, bv, ctx);
    pooled_kernel<<<1024, 256, 0, stream>>>(ctx, Wo, bo, out);
}

// Round 12
// 334.447 us; speedup vs baseline: 1.1403x; 1.0322x over previous
//
#include <hip/hip_runtime.h>
#include <math.h>

#define B_  4
#define L_  2048
#define H_  1024
#define NH_ 16
#define DK_ 64

// 0.125 * log2(e): folded into q so attn scores are already in log2 units
#define QSC 0.18033688011112043f

typedef unsigned short ushort_t;
typedef __attribute__((ext_vector_type(8))) short short8;
typedef __attribute__((ext_vector_type(4))) float f32x4;

__device__ __forceinline__ ushort_t f2b(float f) {   // RNE fp32->bf16
    unsigned int u = __float_as_uint(f);
    return (ushort_t)((u + 0x7FFFu + ((u >> 16) & 1u)) >> 16);
}
__device__ __forceinline__ float b2f(ushort_t h) {
    return __uint_as_float(((unsigned int)h) << 16);
}
__device__ __forceinline__ float fexp2(float x) {
    return __builtin_amdgcn_exp2f(x);
}

__device__ __forceinline__ void gload_lds16(const void* g, void* l) {
    __builtin_amdgcn_global_load_lds((const __attribute__((address_space(1))) void*)g,
                                     (__attribute__((address_space(3))) void*)l, 16, 0, 0);
}

// ---------------------------------------------------------------------------
// RNE split cast for x, Wk (hi+lo) and Wq (hi only) + zero-fill of cs/T.
// bid: [0,8192) x | [8192,9216) Wq(hi) | [9216,10240) Wk | [10240,10432) zero
// ---------------------------------------------------------------------------
__global__ __launch_bounds__(256) void fsplit3_kernel(
    const float* __restrict__ x, const float* __restrict__ Wq, const float* __restrict__ Wk,
    ushort_t* __restrict__ xh, ushort_t* __restrict__ xl,
    ushort_t* __restrict__ wqh,
    ushort_t* __restrict__ wkh, ushort_t* __restrict__ wkl,
    float* __restrict__ zero_dst)
{
    int bid = blockIdx.x;
    if (bid >= 10240) {
        int i = (bid - 10240) * 256 + threadIdx.x;     // 49152 float4 = 768 KB
        ((float4*)zero_dst)[i] = (float4){0.f, 0.f, 0.f, 0.f};
        return;
    }
    if (bid >= 8192 && bid < 9216) {                   // Wq: hi plane only
        int i = (bid - 8192) * 256 + threadIdx.x;
        float4 v = ((const float4*)Wq)[i];
        ushort4 h;
        h.x = f2b(v.x); h.y = f2b(v.y); h.z = f2b(v.z); h.w = f2b(v.w);
        ((ushort4*)wqh)[i] = h;
        return;
    }
    const float* src; ushort_t *ph, *pl; int i;
    if (bid < 8192) { src = x;  ph = xh;  pl = xl;  i = bid * 256 + threadIdx.x; }
    else            { src = Wk; ph = wkh; pl = wkl; i = (bid - 9216) * 256 + threadIdx.x; }
    float4 v = ((const float4*)src)[i];
    float f[4] = {v.x, v.y, v.z, v.w};
    ushort4 h, l;
    ushort_t hh[4], ll[4];
    #pragma unroll
    for (int e = 0; e < 4; ++e) {
        hh[e] = f2b(f[e]);
        ll[e] = f2b(f[e] - b2f(hh[e]));
    }
    h.x = hh[0]; h.y = hh[1]; h.z = hh[2]; h.w = hh[3];
    l.x = ll[0]; l.y = ll[1]; l.z = ll[2]; l.w = ll[3];
    ((ushort4*)ph)[i] = h;
    ((ushort4*)pl)[i] = l;
}

// ---------------------------------------------------------------------------
// Q/K projection. 128x128 tile, BK=32, 256 threads.
// grid = (n-tile 64, o-tile 8, z 2): blocks sharing an n-tile (all o, both z)
// get the same blockIdx.x%8 -> same XCD -> the 512KB xh/xl row-pair is
// fetched into that XCD's L2 once instead of 8x.
// z=0 (q): 1 MFMA ah*Wh. z=1 (k): 3 MFMAs, output split (hi,lo).
// ---------------------------------------------------------------------------
__global__ __launch_bounds__(256) void proj_split(
    const ushort_t* __restrict__ xh, const ushort_t* __restrict__ xl,
    const ushort_t* __restrict__ Wqh,
    const ushort_t* __restrict__ Wkh, const ushort_t* __restrict__ Wkl,
    const float* __restrict__ bq, const float* __restrict__ bk,
    ushort_t* __restrict__ qho,
    ushort_t* __restrict__ kho, ushort_t* __restrict__ klo)
{
    const int z = blockIdx.z;
    const ushort_t* Wh = z ? Wkh : Wqh;
    const ushort_t* Wl = Wkl;
    const float* bias  = z ? bk  : bq;

    const int n0 = blockIdx.x * 128;       // n-tile fastest -> XCD-pinned x
    const int o0 = blockIdx.y * 128;

    __shared__ ushort_t Ash[128 * 32];
    __shared__ ushort_t Asl[128 * 32];
    __shared__ ushort_t Bsh[128 * 32];
    __shared__ ushort_t Bsl[128 * 32];

    const int t = threadIdx.x;
    const int lane = t & 63, w = t >> 6;
    const int ln = lane & 15, qd = lane >> 4;
    const int wy = w >> 1, wx = w & 1;
    const int ldsbase = (t & ~63) * 8;

    int rowS[2], cS[2];
    #pragma unroll
    for (int i = 0; i < 2; ++i) {
        int slot = i * 256 + t;
        rowS[i] = slot >> 2;
        cS[i] = (slot & 3) ^ ((rowS[i] >> 1) & 3);
    }

    f32x4 acc[4][4];
    #pragma unroll
    for (int i = 0; i < 4; ++i)
        #pragma unroll
        for (int j = 0; j < 4; ++j) acc[i][j] = (f32x4){0.f, 0.f, 0.f, 0.f};

    for (int k0 = 0; k0 < H_; k0 += 32) {
        __syncthreads();
        #pragma unroll
        for (int i = 0; i < 2; ++i) {
            gload_lds16(xh + (size_t)(n0 + rowS[i]) * H_ + k0 + cS[i] * 8,
                        &Ash[i * 2048 + ldsbase]);
            gload_lds16(Wh + (size_t)(o0 + rowS[i]) * H_ + k0 + cS[i] * 8,
                        &Bsh[i * 2048 + ldsbase]);
        }
        if (z) {
            #pragma unroll
            for (int i = 0; i < 2; ++i) {
                gload_lds16(xl + (size_t)(n0 + rowS[i]) * H_ + k0 + cS[i] * 8,
                            &Asl[i * 2048 + ldsbase]);
                gload_lds16(Wl + (size_t)(o0 + rowS[i]) * H_ + k0 + cS[i] * 8,
                            &Bsl[i * 2048 + ldsbase]);
            }
        }
        __syncthreads();

        short8 bh4[4], bl4[4];
        #pragma unroll
        for (int nt = 0; nt < 4; ++nt) {
            int row = wx * 64 + nt * 16 + ln;
            int sz = (qd ^ ((row >> 1) & 3)) << 3;
            bh4[nt] = *(const short8*)&Bsh[row * 32 + sz];
            if (z) bl4[nt] = *(const short8*)&Bsl[row * 32 + sz];
        }
        #pragma unroll
        for (int mt = 0; mt < 4; ++mt) {
            int row = wy * 64 + mt * 16 + ln;
            int sz = (qd ^ ((row >> 1) & 3)) << 3;
            short8 ah = *(const short8*)&Ash[row * 32 + sz];
            if (z) {
                short8 al = *(const short8*)&Asl[row * 32 + sz];
                #pragma unroll
                for (int nt = 0; nt < 4; ++nt) {
                    acc[mt][nt] = __builtin_amdgcn_mfma_f32_16x16x32_bf16(al, bh4[nt], acc[mt][nt], 0, 0, 0);
                    acc[mt][nt] = __builtin_amdgcn_mfma_f32_16x16x32_bf16(ah, bl4[nt], acc[mt][nt], 0, 0, 0);
                    acc[mt][nt] = __builtin_amdgcn_mfma_f32_16x16x32_bf16(ah, bh4[nt], acc[mt][nt], 0, 0, 0);
                }
            } else {
                #pragma unroll
                for (int nt = 0; nt < 4; ++nt)
                    acc[mt][nt] = __builtin_amdgcn_mfma_f32_16x16x32_bf16(ah, bh4[nt], acc[mt][nt], 0, 0, 0);
            }
        }
    }

    #pragma unroll
    for (int nt = 0; nt < 4; ++nt) {
        int o = o0 + wx * 64 + nt * 16 + ln;
        float bvv = bias[o];
        int hh = o >> 6, d = o & 63;
        #pragma unroll
        for (int mt = 0; mt < 4; ++mt) {
            #pragma unroll
            for (int r = 0; r < 4; ++r) {
                int n = n0 + wy * 64 + mt * 16 + qd * 4 + r;
                int bb = n >> 11, l = n & (L_ - 1);
                size_t idx = (((size_t)(bb * NH_ + hh) * L_ + l) << 6) + d;
                float val = acc[mt][nt][r] + bvv;
                if (z) {
                    ushort_t vh = f2b(val);
                    kho[idx] = vh;
                    klo[idx] = f2b(val - b2f(vh));
                } else {
                    qho[idx] = f2b(val * QSC);
                }
            }
        }
    }
}

// ---------------------------------------------------------------------------
// Attention column sums cs[b,h,k] = sum_q P[q,k]. q-tile 128/block, 2 A-sets
// per wave. XCD swizzle: bh = blockIdx.x & 63 so all 16 q-tiles of one head
// share blockIdx.x%8 -> one XCD -> K (512KB/head x 8 heads = 4MB) stays in
// that XCD's L2 instead of being HBM-fetched ~8x.
// pass1: qh*kh denominators. pass2: qh*(kh+kl) numerators.
// ---------------------------------------------------------------------------
__global__ __launch_bounds__(256) void attn_split(
    const ushort_t* __restrict__ qh,
    const ushort_t* __restrict__ kh, const ushort_t* __restrict__ kl,
    float* __restrict__ cs)
{
    const int bh = blockIdx.x & 63;        // fastest -> XCD-pinned head
    const int qt = blockIdx.x >> 6;        // 16 q-tiles of 128 rows

    const int t = threadIdx.x;
    const int lane = t & 63, w = t >> 6;
    const int ln = lane & 15, qd = lane >> 4;

    __shared__ ushort_t Ksh[64 * 64];
    __shared__ ushort_t Ksl[64 * 64];
    __shared__ float cs_all[4][64];

    const size_t headoff = (size_t)bh * L_ * DK_;
    const size_t qoff0 = headoff + ((size_t)(qt * 128 + w * 32 + ln)) * DK_;
    const size_t qoff1 = qoff0 + 16 * DK_;
    short8 aqh[2][2];
    aqh[0][0] = *(const short8*)(qh + qoff0 + qd * 8);
    aqh[0][1] = *(const short8*)(qh + qoff0 + 32 + qd * 8);
    aqh[1][0] = *(const short8*)(qh + qoff1 + qd * 8);
    aqh[1][1] = *(const short8*)(qh + qoff1 + 32 + qd * 8);

    int rowS[2], cS[2];
    #pragma unroll
    for (int i = 0; i < 2; ++i) {
        int slot = i * 256 + t;
        rowS[i] = slot >> 3;
        cS[i] = (slot & 7) ^ (rowS[i] & 7);
    }

    float l_run[2][4] = {};

    // ---------------- pass 1: l = sum_k exp2(s_hi) ----------------
    for (int kt = 0; kt < 32; ++kt) {
        __syncthreads();
        #pragma unroll
        for (int i = 0; i < 2; ++i)
            gload_lds16(kh + headoff + ((size_t)(kt * 64 + rowS[i]) << 6) + cS[i] * 8,
                        &Ksh[i * 2048 + (t & ~63) * 8]);
        __syncthreads();

        #pragma unroll
        for (int nt = 0; nt < 4; ++nt) {
            int kr = nt * 16 + ln;
            int sz0 = ((qd     ^ (kr & 7)) << 3);
            int sz1 = (((qd + 4) ^ (kr & 7)) << 3);
            short8 b0h = *(const short8*)&Ksh[kr * 64 + sz0];
            short8 b1h = *(const short8*)&Ksh[kr * 64 + sz1];
            #pragma unroll
            for (int s = 0; s < 2; ++s) {
                f32x4 zz = (f32x4){0.f, 0.f, 0.f, 0.f};
                zz = __builtin_amdgcn_mfma_f32_16x16x32_bf16(aqh[s][0], b0h, zz, 0, 0, 0);
                zz = __builtin_amdgcn_mfma_f32_16x16x32_bf16(aqh[s][1], b1h, zz, 0, 0, 0);
                #pragma unroll
                for (int r = 0; r < 4; ++r)
                    l_run[s][r] += fexp2(zz[r]);
            }
        }
    }

    #pragma unroll
    for (int off = 1; off < 16; off <<= 1)
        #pragma unroll
        for (int s = 0; s < 2; ++s)
            #pragma unroll
            for (int r = 0; r < 4; ++r)
                l_run[s][r] += __shfl_xor(l_run[s][r], off);
    float inv_l[2][4];
    #pragma unroll
    for (int s = 0; s < 2; ++s)
        #pragma unroll
        for (int r = 0; r < 4; ++r) inv_l[s][r] = 1.0f / l_run[s][r];

    // ---------------- pass 2: column sums (k split, q hi) ----------------
    for (int kt = 0; kt < 32; ++kt) {
        __syncthreads();
        #pragma unroll
        for (int i = 0; i < 2; ++i) {
            gload_lds16(kh + headoff + ((size_t)(kt * 64 + rowS[i]) << 6) + cS[i] * 8,
                        &Ksh[i * 2048 + (t & ~63) * 8]);
            gload_lds16(kl + headoff + ((size_t)(kt * 64 + rowS[i]) << 6) + cS[i] * 8,
                        &Ksl[i * 2048 + (t & ~63) * 8]);
        }
        __syncthreads();

        float colp[4];
        #pragma unroll
        for (int nt = 0; nt < 4; ++nt) {
            int kr = nt * 16 + ln;
            int sz0 = ((qd     ^ (kr & 7)) << 3);
            int sz1 = (((qd + 4) ^ (kr & 7)) << 3);
            short8 b0h = *(const short8*)&Ksh[kr * 64 + sz0];
            short8 b1h = *(const short8*)&Ksh[kr * 64 + sz1];
            short8 b0l = *(const short8*)&Ksl[kr * 64 + sz0];
            short8 b1l = *(const short8*)&Ksl[kr * 64 + sz1];
            float cp = 0.f;
            #pragma unroll
            for (int s = 0; s < 2; ++s) {
                f32x4 zz = (f32x4){0.f, 0.f, 0.f, 0.f};
                zz = __builtin_amdgcn_mfma_f32_16x16x32_bf16(aqh[s][0], b0l, zz, 0, 0, 0);
                zz = __builtin_amdgcn_mfma_f32_16x16x32_bf16(aqh[s][1], b1l, zz, 0, 0, 0);
                zz = __builtin_amdgcn_mfma_f32_16x16x32_bf16(aqh[s][0], b0h, zz, 0, 0, 0);
                zz = __builtin_amdgcn_mfma_f32_16x16x32_bf16(aqh[s][1], b1h, zz, 0, 0, 0);
                cp += fexp2(zz[0]) * inv_l[s][0] + fexp2(zz[1]) * inv_l[s][1]
                    + fexp2(zz[2]) * inv_l[s][2] + fexp2(zz[3]) * inv_l[s][3];
            }
            colp[nt] = cp;
        }
        #pragma unroll
        for (int nt = 0; nt < 4; ++nt) {
            colp[nt] += __shfl_xor(colp[nt], 16);
            colp[nt] += __shfl_xor(colp[nt], 32);
        }
        float mine = (qd == 0) ? colp[0] : (qd == 1) ? colp[1] : (qd == 2) ? colp[2] : colp[3];
        cs_all[w][lane] = mine;
        __syncthreads();
        if (t < 64) {
            float tot = cs_all[0][t] + cs_all[1][t] + cs_all[2][t] + cs_all[3][t];
            atomicAdd(&cs[(size_t)bh * L_ + kt * 64 + t], tot);
        }
    }
}

// ---------------------------------------------------------------------------
// T[b,h,h'] = sum_l cs[b,h,l] * x[b,l,h']  (fp32, atomic over 8 l-splits)
// + blocks with o-chunk 0 also emit weights[b,l] = sum_h cs[b,h,l]/(NH*L)
// ---------------------------------------------------------------------------
__global__ __launch_bounds__(256) void ctx1_kernel(
    const float* __restrict__ cs, const float* __restrict__ x,
    float* __restrict__ T, float* __restrict__ out)
{
    const int o0 = blockIdx.x * 64, b = blockIdx.y, l0 = blockIdx.z * 256;
    const int t = threadIdx.x, o = t & 63, hg = t >> 6;
    __shared__ float cs_s[16][128];
    float acc[4] = {};

    for (int ch = 0; ch < 2; ++ch) {
        int lbase = l0 + ch * 128;
        __syncthreads();
        for (int i = t; i < 2048; i += 256) {
            int h = i >> 7, lc = i & 127;
            cs_s[h][lc] = cs[((size_t)(b * NH_ + h) << 11) + lbase + lc];
        }
        __syncthreads();
        if (blockIdx.x == 0 && t < 128) {      // weights fused here
            float s = 0.f;
            #pragma unroll
            for (int h = 0; h < NH_; ++h) s += cs_s[h][t];
            out[B_ * H_ + b * L_ + lbase + t] = s * (1.0f / (float)(NH_ * L_));
        }
        for (int lc = 0; lc < 128; ++lc) {
            float xv = x[((size_t)(b * L_ + lbase + lc) << 10) + o0 + o];
            #pragma unroll
            for (int j = 0; j < 4; ++j) acc[j] += cs_s[hg * 4 + j][lc] * xv;
        }
    }
    #pragma unroll
    for (int j = 0; j < 4; ++j)
        atomicAdd(&T[((size_t)(b * NH_ + hg * 4 + j) << 10) + o0 + o], acc[j]);
}

// ---------------------------------------------------------------------------
// ctx[b,o] = sum_h' T[b, o>>6, h'] * Wv[o,h'] + L*bv[o]; wave per row
// ---------------------------------------------------------------------------
__global__ __launch_bounds__(256) void ctx2_kernel(
    const float* __restrict__ T, const float* __restrict__ Wv,
    const float* __restrict__ bv, float* __restrict__ ctx)
{
    const int gid  = blockIdx.x * 4 + (threadIdx.x >> 6);
    const int lane = threadIdx.x & 63;
    const int b = gid >> 10, o = gid & (H_ - 1);
    const float4* wr = (const float4*)(Wv + (size_t)o * H_);
    const float4* tr = (const float4*)(T + ((size_t)(b * NH_ + (o >> 6)) << 10));
    float acc = 0.f;
    #pragma unroll
    for (int i = 0; i < 4; ++i) {
        float4 wv = wr[lane + i * 64];
        float4 tv = tr[lane + i * 64];
        acc += wv.x * tv.x + wv.y * tv.y + wv.z * tv.z + wv.w * tv.w;
    }
    #pragma unroll
    for (int off = 32; off; off >>= 1) acc += __shfl_xor(acc, off);
    if (lane == 0) ctx[(b << 10) + o] = acc + (float)L_ * bv[o];
}

// ---------------------------------------------------------------------------
// pooled[b,o] = bo[o] + (1/L) * sum_h ctx[b,h] * Wo[o,h]; wave per row
// ---------------------------------------------------------------------------
__global__ __launch_bounds__(256) void pooled_kernel(
    const float* __restrict__ ctx, const float* __restrict__ Wo,
    const float* __restrict__ bo, float* __restrict__ out)
{
    const int gid  = blockIdx.x * 4 + (threadIdx.x >> 6);
    const int lane = threadIdx.x & 63;
    const int b = gid >> 10, o = gid & (H_ - 1);
    const float4* wr = (const float4*)(Wo + (size_t)o * H_);
    const float4* cr = (const float4*)(ctx + ((size_t)b << 10));
    float acc = 0.f;
    #pragma unroll
    for (int i = 0; i < 4; ++i) {
        float4 wv = wr[lane + i * 64];
        float4 cv = cr[lane + i * 64];
        acc += wv.x * cv.x + wv.y * cv.y + wv.z * cv.z + wv.w * cv.w;
    }
    #pragma unroll
    for (int off = 32; off; off >>= 1) acc += __shfl_xor(acc, off);
    if (lane == 0) out[(b << 10) + o] = acc * (1.0f / (float)L_) + bo[o];
}

// ---------------------------------------------------------------------------
extern "C" void kernel_launch(void* const* d_in, const int* in_sizes, int n_in,
                              void* d_out, int out_size, void* d_ws, size_t ws_size,
                              hipStream_t stream)
{
    const float* x  = (const float*)d_in[0];
    const float* Wq = (const float*)d_in[1];
    const float* bq = (const float*)d_in[2];
    const float* Wk = (const float*)d_in[3];
    const float* bk = (const float*)d_in[4];
    const float* Wv = (const float*)d_in[5];
    const float* bv = (const float*)d_in[6];
    const float* Wo = (const float*)d_in[7];
    const float* bo = (const float*)d_in[8];
    float* out = (float*)d_out;

    float* ws  = (float*)d_ws;
    float* cs  = ws;                       // B*NH*L = 131072 f
    float* T   = ws + 131072;              // B*NH*H =  65536 f
    float* ctx = ws + 196608;              // B*H    =   4096 f
    ushort_t* base = (ushort_t*)(ws + 200704);
    const size_t QE = 8388608;             // B*NH*L*DK == B*L*H
    ushort_t* qhb = base;
    ushort_t* khb = base + QE;
    ushort_t* klb = base + 2 * QE;
    ushort_t* xhb = base + 3 * QE;
    ushort_t* xlb = base + 4 * QE;
    ushort_t* wqh = base + 5 * QE;
    ushort_t* wkh = wqh + 1048576;
    ushort_t* wkl = wkh + 1048576;

    // fsplit3 also zeroes cs+T (first 196608 floats of ws)
    fsplit3_kernel<<<10432, 256, 0, stream>>>(x, Wq, Wk, xhb, xlb,
                                              wqh, wkh, wkl, ws);

    proj_split<<<dim3(64, 8, 2), 256, 0, stream>>>(xhb, xlb, wqh, wkh, wkl,
                                                   bq, bk, qhb, khb, klb);

    attn_split<<<B_ * NH_ * (L_ / 128), 256, 0, stream>>>(qhb, khb, klb, cs);

    ctx1_kernel<<<dim3(16, 4, 8), 256, 0, stream>>>(cs, x, T, out);
    ctx2_kernel<<<1024, 256, 0, stream>>>(T, Wv, bv, ctx);
    pooled_kernel<<<1024, 256, 0, stream>>>(ctx, Wo, bo, out);
}